// Round 5
// baseline (366.627 us; speedup 1.0000x reference)
//
#include <hip/hip_runtime.h>
#include <hip/hip_bf16.h>

#define NV_N 32
#define NV_C 128
#define NV_K 64
#define NV_S 12544
#define ST 64          // s-columns per tile
#define TILES 7        // tiles per block
#define SCHUNK 28      // blocks per image (896 blocks total)
#define AS 72          // a_lds[k][s] stride (bf16 elems): 144 B rows, 16B-aligned

typedef short short8 __attribute__((ext_vector_type(8)));
typedef float floatx4 __attribute__((ext_vector_type(4)));

static __device__ __forceinline__ unsigned short f2bf(float f) {
  union { float f; unsigned u; } v; v.f = f;
  unsigned r = v.u + 0x7FFFu + ((v.u >> 16) & 1u);  // RNE
  return (unsigned short)(r >> 16);
}
static __device__ __forceinline__ unsigned pk2(float a, float b) {
  union { __hip_bfloat162 h; unsigned u; } v;
  v.h = __float22bfloat162_rn(make_float2(a, b));   // v_cvt_pk_bf16_f32
  return v.u;
}
static __device__ __forceinline__ short8 pack8(float4 a, float4 b) {
  union { unsigned u[4]; short8 s; } r;
  r.u[0] = pk2(a.x, a.y); r.u[1] = pk2(a.z, a.w);
  r.u[2] = pk2(b.x, b.y); r.u[3] = pk2(b.z, b.w);
  return r.s;
}
static __device__ __forceinline__ short8 pack8s(const float* f) {
  union { unsigned u[4]; short8 s; } r;
  r.u[0] = pk2(f[0], f[1]); r.u[1] = pk2(f[2], f[3]);
  r.u[2] = pk2(f[4], f[5]); r.u[3] = pk2(f[6], f[7]);
  return r.s;
}

// k-split GEMM1: wave w computes k-half (w>>1) for s-subtiles {2*(w&1), 2*(w&1)+1}.
// GEMM2 keeps full k per wave (a comes from LDS). 4 waves/SIMD target.
__global__ __launch_bounds__(256, 4) void netvlad_main(
    const float* __restrict__ x, const float* __restrict__ conv_w,
    float* __restrict__ vlad_ws, float* __restrict__ asum_ws) {
  __shared__ __attribute__((aligned(16))) unsigned short a_lds[2][NV_K * AS]; // 18432 B
  __shared__ float sum_lds[2][2][ST];                                         //  1024 B
  __shared__ float asum_sh[4][32];                                            //   512 B

  const int t = threadIdx.x;
  const int n = blockIdx.x / SCHUNK;
  const int chunk = blockIdx.x % SCHUNK;
  const int s_base = chunk * (ST * TILES);
  const int w = t >> 6;        // wave 0..3
  const int lane = t & 63;
  const int q = lane >> 4;     // quad 0..3
  const int l = lane & 15;
  const int kh = w >> 1;       // k-half for GEMM1
  const int sp = w & 1;        // s-subtile pair for GEMM1

  const float* __restrict__ xn = x + (size_t)n * NV_C * NV_S;

  // W A-frags for this wave's 32 k only: W[kh*32+mt2*16+l][kc*32+q*8+j]
  short8 wfrag[2][4];
#pragma unroll
  for (int mt2 = 0; mt2 < 2; ++mt2)
#pragma unroll
    for (int kc = 0; kc < 4; ++kc) {
      const float* wp = conv_w + (kh * 32 + mt2 * 16 + l) * NV_C + kc * 32 + q * 8;
      wfrag[mt2][kc] = pack8(*(const float4*)wp, *(const float4*)(wp + 4));
    }

  floatx4 acc2[4][2];   // vlad acc: k=mt*16+q*4+r, c=(w*2+nt)*16+l (full k)
  float asum8[2][4];    // asum partials for k = kh*32 + mt2*16 + q*4 + r
#pragma unroll
  for (int mt = 0; mt < 4; ++mt)
#pragma unroll
    for (int nt = 0; nt < 2; ++nt) acc2[mt][nt] = (floatx4){0.f, 0.f, 0.f, 0.f};
#pragma unroll
  for (int mt2 = 0; mt2 < 2; ++mt2)
#pragma unroll
    for (int r = 0; r < 4; ++r) asum8[mt2][r] = 0.f;

  // GEMM1 B bases: column s = s_base + (2*sp+st2)*16 + l, row base q*8
  const float* __restrict__ xg1_0 = xn + (size_t)(q * 8) * NV_S + s_base + (2 * sp + 0) * 16 + l;
  const float* __restrict__ xg1_1 = xg1_0 + 16;
  // GEMM2 B bases: row c = (w*2+nt)*16 + l, col base s_base + q*8
  const float* __restrict__ xg2a = xn + (size_t)((w * 2 + 0) * 16 + l) * NV_S + s_base + q * 8;
  const float* __restrict__ xg2b = xn + (size_t)((w * 2 + 1) * 16 + l) * NV_S + s_base + q * 8;

  for (int tt = 0; tt < TILES; ++tt) {
    const int buf = tt & 1;
    const int so = tt * ST;

    // ---- GEMM1: this wave's 32k x 32s ----
    floatx4 acc1[2][2];
#pragma unroll
    for (int mt2 = 0; mt2 < 2; ++mt2)
#pragma unroll
      for (int st2 = 0; st2 < 2; ++st2) acc1[mt2][st2] = (floatx4){0.f, 0.f, 0.f, 0.f};

#pragma unroll
    for (int st2 = 0; st2 < 2; ++st2) {
      const float* __restrict__ xb = st2 ? xg1_1 : xg1_0;
#pragma unroll
      for (int kc = 0; kc < 4; ++kc) {
        float bx[8];
#pragma unroll
        for (int j = 0; j < 8; ++j)
          bx[j] = xb[(size_t)(kc * 32 + j) * NV_S + so];
        const short8 bfr = pack8s(bx);
#pragma unroll
        for (int mt2 = 0; mt2 < 2; ++mt2)
          acc1[mt2][st2] = __builtin_amdgcn_mfma_f32_16x16x32_bf16(wfrag[mt2][kc], bfr, acc1[mt2][st2], 0, 0, 0);
      }
    }

    // ---- exp + per-wave (32-k) column sums; exchange halves via LDS ----
    {
      float colp[2];
#pragma unroll
      for (int st2 = 0; st2 < 2; ++st2) {
        float s = 0.f;
#pragma unroll
        for (int mt2 = 0; mt2 < 2; ++mt2)
#pragma unroll
          for (int r = 0; r < 4; ++r) {
            float e = __expf(acc1[mt2][st2][r]);  // shift-invariant softmax; |logit|<~4
            acc1[mt2][st2][r] = e; s += e;
          }
        s += __shfl_xor(s, 16);
        s += __shfl_xor(s, 32);
        colp[st2] = s;
      }
      if (q == 0) {
        sum_lds[buf][kh][(2 * sp + 0) * 16 + l] = colp[0];
        sum_lds[buf][kh][(2 * sp + 1) * 16 + l] = colp[1];
      }
    }
    __syncthreads();  // B1: both k-half sums available

#pragma unroll
    for (int st2 = 0; st2 < 2; ++st2) {
      const int si = (2 * sp + st2) * 16 + l;
      const float inv = 1.0f / (sum_lds[buf][0][si] + sum_lds[buf][1][si]);
#pragma unroll
      for (int mt2 = 0; mt2 < 2; ++mt2)
#pragma unroll
        for (int r = 0; r < 4; ++r) {
          float a = acc1[mt2][st2][r] * inv;
          asum8[mt2][r] += a;
          a_lds[buf][(kh * 32 + mt2 * 16 + q * 4 + r) * AS + si] = f2bf(a);
        }
    }
    __syncthreads();  // B2: a_lds complete (dbuf keeps 2 barriers/tile safe)

    // ---- GEMM2: vlad[64k][128c] += a(64x64) * x^T ----
#pragma unroll
    for (int sk = 0; sk < 2; ++sk) {
      short8 afr[4];
#pragma unroll
      for (int mt = 0; mt < 4; ++mt)
        afr[mt] = *(const short8*)&a_lds[buf][(mt * 16 + l) * AS + sk * 32 + q * 8];
      {
        const short8 b0 = pack8(*(const float4*)(xg2a + so + sk * 32),
                                *(const float4*)(xg2a + so + sk * 32 + 4));
#pragma unroll
        for (int mt = 0; mt < 4; ++mt)
          acc2[mt][0] = __builtin_amdgcn_mfma_f32_16x16x32_bf16(afr[mt], b0, acc2[mt][0], 0, 0, 0);
      }
      {
        const short8 b1 = pack8(*(const float4*)(xg2b + so + sk * 32),
                                *(const float4*)(xg2b + so + sk * 32 + 4));
#pragma unroll
        for (int mt = 0; mt < 4; ++mt)
          acc2[mt][1] = __builtin_amdgcn_mfma_f32_16x16x32_bf16(afr[mt], b1, acc2[mt][1], 0, 0, 0);
      }
    }
  }

  // ---- epilogue: per-chunk partials, no atomics ----
#pragma unroll
  for (int mt2 = 0; mt2 < 2; ++mt2)
#pragma unroll
    for (int r = 0; r < 4; ++r) {
      float v = asum8[mt2][r];
      v += __shfl_xor(v, 1); v += __shfl_xor(v, 2);
      v += __shfl_xor(v, 4); v += __shfl_xor(v, 8);
      if (l == 0) asum_sh[w][mt2 * 16 + q * 4 + r] = v;  // local k within k-half
    }
  __syncthreads();
  const size_t slab = (size_t)(n * SCHUNK + chunk);
  if (t < NV_K)
    asum_ws[slab * NV_K + t] =
        asum_sh[2 * (t >> 5)][t & 31] + asum_sh[2 * (t >> 5) + 1][t & 31];

  float* vw = vlad_ws + slab * (NV_K * NV_C);
#pragma unroll
  for (int mt = 0; mt < 4; ++mt)
#pragma unroll
    for (int nt = 0; nt < 2; ++nt)
#pragma unroll
      for (int r = 0; r < 4; ++r)
        vw[(mt * 16 + q * 4 + r) * NV_C + (w * 2 + nt) * 16 + l] = acc2[mt][nt][r];
}

// Fused tail: 32 blocks (one per image). Sum 28 chunk partials, subtract
// asum*centroid, intra-norm per cluster, global L2 norm, write out.
__global__ __launch_bounds__(256) void netvlad_tail(
    const float* __restrict__ vlad_ws, const float* __restrict__ asum_ws,
    const float* __restrict__ cent, float* __restrict__ out) {
  __shared__ float asum_l[NV_K];
  __shared__ float rowss[NV_K][33];   // +1 pad
  __shared__ float red[256];
  __shared__ float rscale[NV_K];
  __shared__ float gscale_sh;

  const int t = threadIdx.x; const int n = blockIdx.x;
  const int g = t >> 5;          // 0..7
  const int c4 = (t & 31) * 4;   // column group

  if (t < NV_K) {
    float s = 0.f;
#pragma unroll
    for (int ch = 0; ch < SCHUNK; ++ch)
      s += asum_ws[(size_t)(n * SCHUNK + ch) * NV_K + t];
    asum_l[t] = s;
  }

  float4 acc[8];
#pragma unroll
  for (int i = 0; i < 8; ++i) acc[i] = (float4){0.f, 0.f, 0.f, 0.f};
  for (int ch = 0; ch < SCHUNK; ++ch) {
    const float* base = vlad_ws + (size_t)(n * SCHUNK + ch) * (NV_K * NV_C);
#pragma unroll
    for (int i = 0; i < 8; ++i) {
      float4 p = *(const float4*)(base + i * 1024 + t * 4);
      acc[i].x += p.x; acc[i].y += p.y; acc[i].z += p.z; acc[i].w += p.w;
    }
  }
  __syncthreads();  // asum_l ready

  float ss[8];
#pragma unroll
  for (int i = 0; i < 8; ++i) {
    const int k = i * 8 + g;
    const float as = asum_l[k];
    float4 ce = *(const float4*)&cent[k * NV_C + c4];
    acc[i].x -= as * ce.x; acc[i].y -= as * ce.y;
    acc[i].z -= as * ce.z; acc[i].w -= as * ce.w;
    ss[i] = acc[i].x * acc[i].x + acc[i].y * acc[i].y +
            acc[i].z * acc[i].z + acc[i].w * acc[i].w;
    rowss[k][t & 31] = ss[i];
  }
  __syncthreads();
  if (t < NV_K) {
    float s = 0.f;
#pragma unroll
    for (int j = 0; j < 32; ++j) s += rowss[t][j];
    rscale[t] = 1.0f / fmaxf(sqrtf(s), 1e-12f);
  }
  __syncthreads();

  float gp = 0.f;
#pragma unroll
  for (int i = 0; i < 8; ++i) {
    const float rs = rscale[i * 8 + g];
    gp += ss[i] * rs * rs;
  }
  red[t] = gp;
  __syncthreads();
  if (t < 64) {
    float s = red[t] + red[t + 64] + red[t + 128] + red[t + 192];
#pragma unroll
    for (int o = 32; o > 0; o >>= 1) s += __shfl_down(s, o);
    if (t == 0) gscale_sh = 1.0f / fmaxf(sqrtf(s), 1e-12f);
  }
  __syncthreads();
  const float gs = gscale_sh;

#pragma unroll
  for (int i = 0; i < 8; ++i) {
    const int k = i * 8 + g;
    const float sc = rscale[k] * gs;
    float4 v = acc[i];
    v.x *= sc; v.y *= sc; v.z *= sc; v.w *= sc;
    *(float4*)(out + (size_t)n * (NV_K * NV_C) + i * 1024 + t * 4) = v;
  }
}

extern "C" void kernel_launch(void* const* d_in, const int* in_sizes, int n_in,
                              void* d_out, int out_size, void* d_ws, size_t ws_size,
                              hipStream_t stream) {
  (void)in_sizes; (void)n_in; (void)out_size; (void)ws_size;
  const float* x      = (const float*)d_in[0];
  const float* conv_w = (const float*)d_in[1];
  const float* cent   = (const float*)d_in[2];
  float* out = (float*)d_out;

  float* vlad_ws = (float*)d_ws;                                    // 896 * 8192 floats
  float* asum_ws = vlad_ws + (size_t)NV_N * SCHUNK * NV_K * NV_C;   // 896 * 64

  hipLaunchKernelGGL(netvlad_main, dim3(NV_N * SCHUNK), dim3(256), 0, stream,
                     x, conv_w, vlad_ws, asum_ws);
  hipLaunchKernelGGL(netvlad_tail, dim3(NV_N), dim3(256), 0, stream,
                     vlad_ws, asum_ws, cent, out);
}